// Round 5
// baseline (354.066 us; speedup 1.0000x reference)
//
#include <hip/hip_runtime.h>
#include <stdint.h>

#define NCELL (512 * 512)
#define DIN   136

// output layout (flat f32, concat in return order)
#define OUT_LAT 2097152ull                 // N*8
#define OUT_C   35651584ull                // OUT_LAT + N*128
#define OUT_H   52428800ull                // OUT_C + N*64

// packed-weight offsets in d_ws (bf16 elements)
#define WPRE_OFF  0        // [5][64][32]   = 10240
#define W2_OFF    10240    // [4][256][32]  = 32768
#define WPOST_OFF 43008    // [2][160][32]  = 10240 ; n' 0..7 dyn, 8..31 pad, 32..159 lat
#define WTOTAL    53248

// LDS: one buffer, 64 rows x 400B = 25600B -> 6 blocks/CU.
// 400B = 100 dwords; 100 mod 32 = 4 -> 16-row b128 frag reads are 2-way (free).
// row layout: [0..271] X cols 0..135 (GEMM1); [272..399] h_prev.
// after GEMM1 sync: [0..127] pre. LSTM writes hn -> [128..255] (dead X cols 64..127).
#define ROWB  400
#define HOFF  272
#define HNOFF 128

typedef __bf16 bf16x8 __attribute__((ext_vector_type(8)));
typedef float  f32x4  __attribute__((ext_vector_type(4)));

__device__ __forceinline__ unsigned short f2bf(float f) {
    unsigned int u = __float_as_uint(f);
    u += 0x7FFF + ((u >> 16) & 1);          // round-to-nearest-even
    return (unsigned short)(u >> 16);
}
__device__ __forceinline__ int pack2(float a, float b) {
    return (int)f2bf(a) | ((int)f2bf(b) << 16);
}
__device__ __forceinline__ float fast_sigmoid(float x) {
    return __builtin_amdgcn_rcpf(1.f + __expf(-x));
}
__device__ __forceinline__ float fast_tanh(float x) {
    float e = __expf(2.f * x);              // inf-safe: rcp(inf)=0 -> 1; e->0 -> -1
    return 1.f - 2.f * __builtin_amdgcn_rcpf(e + 1.f);
}
__device__ __forceinline__ float bf2f_lo(int u) {
    return __uint_as_float((unsigned)u << 16);
}
__device__ __forceinline__ float bf2f_hi(int u) {
    return __uint_as_float((unsigned)u & 0xffff0000u);
}

// Repack weights to bf16, MFMA-B-fragment-friendly: [K/32][Ncol][32]
__global__ void prep_weights(const float* __restrict__ Wpre,
                             const float* __restrict__ Wih,
                             const float* __restrict__ Whh,
                             const float* __restrict__ Wpost,
                             unsigned short* __restrict__ ws) {
    int i = blockIdx.x * 256 + threadIdx.x;
    if (i < 10240) {                                   // Wpre' : K 136->160 pad, N=64
        int k = i & 31, n = (i >> 5) & 63, s = i >> 11;
        int K = s * 32 + k;
        ws[i] = (K < DIN) ? f2bf(Wpre[K * 64 + n]) : (unsigned short)0;
    } else if (i < 43008) {                            // W2'   : K=128 (ih||hh), N=256
        int j = i - 10240;
        int k = j & 31, n = (j >> 5) & 255, s = j >> 13;
        int K = s * 32 + k;
        float v = (K < 64) ? Wih[K * 256 + n] : Whh[(K - 64) * 256 + n];
        ws[i] = f2bf(v);
    } else if (i < WTOTAL) {                           // Wpost2: [2][160][32], line-aligned
        int j = i - 43008;
        int k = j & 31;
        int t2 = j >> 5;            // 0..319
        int n = t2 % 160;
        int s = t2 / 160;
        int K = s * 32 + k;         // 0..63
        float v = 0.f;
        if (n < 8)        v = Wpost[K * DIN + n];          // dyn cols
        else if (n >= 32) v = Wpost[K * DIN + (n - 24)];   // lat cols 0..127
        ws[i] = f2bf(v);
    }
}

// Cooperative fused kernel: block = 256 threads (4 waves) = 64 cells.
// 6 blocks/CU target: 25.6KB LDS + two-pass GEMM2 (peak acc 32).
__global__ __launch_bounds__(256, 6) void knet_fused(
    const float* __restrict__ dyn_in,
    const float* __restrict__ lat_prev,
    const float* __restrict__ lstm_c,
    const float* __restrict__ lstm_h,
    const int*   __restrict__ coming_from,
    const unsigned short* __restrict__ wsp,
    const float* __restrict__ b_pre,
    const float* __restrict__ b_lstm,
    const float* __restrict__ b_post,
    float* __restrict__ out) {
    __shared__ __align__(16) char Ls[64 * ROWB];

    const int t  = threadIdx.x;
    const int p0 = blockIdx.x * 64;
    const unsigned short* wpre_p  = wsp + WPRE_OFF;
    const unsigned short* w2_p    = wsp + W2_OFF;
    const unsigned short* wpost_p = wsp + WPOST_OFF;

    // ---------------- phase 0: staging ----------------
    {   // h_prev -> bytes 272..399 (bf16), 16 values/thread
        int r = t >> 2, q = t & 3;
        const float4* hp = (const float4*)(lstm_h + (size_t)(p0 + r) * 64 + q * 16);
        float4 v0 = hp[0], v1 = hp[1], v2 = hp[2], v3 = hp[3];
        char* dsth = Ls + r * ROWB + HOFF + q * 32;
        *(int4*)dsth = int4{pack2(v0.x, v0.y), pack2(v0.z, v0.w),
                            pack2(v1.x, v1.y), pack2(v1.z, v1.w)};
        *(int4*)(dsth + 16) = int4{pack2(v2.x, v2.y), pack2(v2.z, v2.w),
                                   pack2(v3.x, v3.y), pack2(v3.z, v3.w)};
    }
    if (t < 128) {  // dyn_in -> X cols 0..7
        int r = t >> 1, c = (t & 1) * 4;
        float4 v = *(const float4*)(dyn_in + (size_t)(p0 + r) * 8 + c);
        int2 wv{pack2(v.x, v.y), pack2(v.z, v.w)};
        *(int2*)(Ls + r * ROWB + c * 2) = wv;
    }
#pragma unroll
    for (int qq = 0; qq < 2; ++qq) {  // lat gather -> X cols 8..135
        int q = t + qq * 256;
        int r = q >> 3, d = q & 7;
        int src = coming_from[(size_t)d * NCELL + p0 + r];
        const float4* lp = (const float4*)(lat_prev + (size_t)src * 128 + d * 16);
        float4 v0 = lp[0], v1 = lp[1], v2 = lp[2], v3 = lp[3];
        char* dst = Ls + r * ROWB + 16 + 32 * d;
        *(int4*)dst = int4{pack2(v0.x, v0.y), pack2(v0.z, v0.w),
                           pack2(v1.x, v1.y), pack2(v1.z, v1.w)};
        *(int4*)(dst + 16) = int4{pack2(v2.x, v2.y), pack2(v2.z, v2.w),
                                  pack2(v3.x, v3.y), pack2(v3.z, v3.w)};
    }
    __syncthreads();

    const int lane = t & 63;
    const int w    = t >> 6;     // wave id = N-tile owner
    const int lr   = lane & 15;
    const int lg   = lane >> 4;

    // ---------------- GEMM1: X[64x(136->160)] @ Wpre'[160x64] -> pre ----------------
    {
        f32x4 acc1[4];
#pragma unroll
        for (int m = 0; m < 4; ++m) acc1[m] = (f32x4){0.f, 0.f, 0.f, 0.f};
#pragma unroll
        for (int s = 0; s < 4; ++s) {
            bf16x8 b = *(const bf16x8*)(wpre_p + ((s * 64 + w * 16 + lr) * 32 + lg * 8));
#pragma unroll
            for (int m = 0; m < 4; ++m) {
                bf16x8 a = *(const bf16x8*)(Ls + (m * 16 + lr) * ROWB + s * 64 + lg * 16);
                acc1[m] = __builtin_amdgcn_mfma_f32_16x16x32_bf16(a, b, acc1[m], 0, 0, 0);
            }
        }
        {   // s=4: A cols 128..159 = {cols 128..135 (lg==0), zeros}
            bf16x8 b4 = *(const bf16x8*)(wpre_p + ((4 * 64 + w * 16 + lr) * 32 + lg * 8));
#pragma unroll
            for (int m = 0; m < 4; ++m) {
                bf16x8 a4 = {};
                if (lg == 0)
                    a4 = *(const bf16x8*)(Ls + (m * 16 + lr) * ROWB + 256);
                acc1[m] = __builtin_amdgcn_mfma_f32_16x16x32_bf16(a4, b4, acc1[m], 0, 0, 0);
            }
        }
        float bp = b_pre[w * 16 + lr];
        int colb = (w * 16 + lr) * 2;
#pragma unroll
        for (int m = 0; m < 4; ++m)
#pragma unroll
            for (int rr = 0; rr < 4; ++rr) {
                int row = m * 16 + lg * 4 + rr;
                float pv = fast_tanh(acc1[m][rr] + bp);
                *(unsigned short*)(Ls + row * ROWB + colb) = f2bf(pv);
            }
    }
    __syncthreads();   // pre visible; X bytes 0..255 reads retired

    // ---------------- GEMM2: [pre||h][64x128] @ W2'[128x256], 2 passes + LSTM -------
    {
        const int hid = w * 16 + lr;
        const float bi = b_lstm[hid],       bg = b_lstm[128 + hid];
        const float bf = b_lstm[64 + hid],  bo = b_lstm[192 + hid];

        // ---- pass A: i (tile w), g (tile w+8) ----
        f32x4 acc[4][2];
#pragma unroll
        for (int m = 0; m < 4; ++m)
#pragma unroll
            for (int j = 0; j < 2; ++j) acc[m][j] = (f32x4){0.f, 0.f, 0.f, 0.f};
#pragma unroll
        for (int s = 0; s < 4; ++s) {
            const int abyte = (s < 2) ? (s * 64 + lg * 16) : (HOFF + (s - 2) * 64 + lg * 16);
            bf16x8 b0 = *(const bf16x8*)(w2_p + ((s * 256 + (w)     * 16 + lr) * 32 + lg * 8));
            bf16x8 b1 = *(const bf16x8*)(w2_p + ((s * 256 + (w + 8) * 16 + lr) * 32 + lg * 8));
#pragma unroll
            for (int m = 0; m < 4; ++m) {
                bf16x8 a = *(const bf16x8*)(Ls + (m * 16 + lr) * ROWB + abyte);
                acc[m][0] = __builtin_amdgcn_mfma_f32_16x16x32_bf16(a, b0, acc[m][0], 0, 0, 0);
                acc[m][1] = __builtin_amdgcn_mfma_f32_16x16x32_bf16(a, b1, acc[m][1], 0, 0, 0);
            }
        }
        // ig = sigmoid(i)*tanh(g), packed bf16 (8 regs)
        int igp[8];
#pragma unroll
        for (int m = 0; m < 4; ++m)
#pragma unroll
            for (int pp = 0; pp < 2; ++pp) {
                float g0 = fast_sigmoid(acc[m][0][2 * pp]     + bi) *
                           fast_tanh(acc[m][1][2 * pp]     + bg);
                float g1 = fast_sigmoid(acc[m][0][2 * pp + 1] + bi) *
                           fast_tanh(acc[m][1][2 * pp + 1] + bg);
                igp[m * 2 + pp] = pack2(g0, g1);
            }

        // prefetch c_old (hidden under pass B MFMAs)
        float cpf[16];
#pragma unroll
        for (int m = 0; m < 4; ++m)
#pragma unroll
            for (int rr = 0; rr < 4; ++rr)
                cpf[m * 4 + rr] =
                    lstm_c[(size_t)(p0 + m * 16 + lg * 4 + rr) * 64 + hid];

        // ---- pass B: f (tile w+4), o (tile w+12) ----
#pragma unroll
        for (int m = 0; m < 4; ++m)
#pragma unroll
            for (int j = 0; j < 2; ++j) acc[m][j] = (f32x4){0.f, 0.f, 0.f, 0.f};
#pragma unroll
        for (int s = 0; s < 4; ++s) {
            const int abyte = (s < 2) ? (s * 64 + lg * 16) : (HOFF + (s - 2) * 64 + lg * 16);
            bf16x8 b0 = *(const bf16x8*)(w2_p + ((s * 256 + (w + 4)  * 16 + lr) * 32 + lg * 8));
            bf16x8 b1 = *(const bf16x8*)(w2_p + ((s * 256 + (w + 12) * 16 + lr) * 32 + lg * 8));
#pragma unroll
            for (int m = 0; m < 4; ++m) {
                bf16x8 a = *(const bf16x8*)(Ls + (m * 16 + lr) * ROWB + abyte);
                acc[m][0] = __builtin_amdgcn_mfma_f32_16x16x32_bf16(a, b0, acc[m][0], 0, 0, 0);
                acc[m][1] = __builtin_amdgcn_mfma_f32_16x16x32_bf16(a, b1, acc[m][1], 0, 0, 0);
            }
        }
        // ---- LSTM pointwise: c -> global (f32 direct), hn -> LDS bytes 128..255 ----
#pragma unroll
        for (int m = 0; m < 4; ++m)
#pragma unroll
            for (int rr = 0; rr < 4; ++rr) {
                int row = m * 16 + lg * 4 + rr;
                size_t cell = (size_t)(p0 + row);
                float fv = fast_sigmoid(acc[m][0][rr] + bf);
                float ov = fast_sigmoid(acc[m][1][rr] + bo);
                float igv = (rr & 1) ? bf2f_hi(igp[m * 2 + (rr >> 1)])
                                     : bf2f_lo(igp[m * 2 + (rr >> 1)]);
                float cn = fv * cpf[m * 4 + rr] + igv;
                float hn = ov * fast_tanh(cn);
                out[OUT_C + cell * 64 + hid] = cn;
                *(unsigned short*)(Ls + row * ROWB + HNOFF + 2 * hid) = f2bf(hn);
            }
    }
    __syncthreads();   // hn visible

    // ---------------- cooperative full-line h stores ----------------
    {
        int r = t >> 2, q = t & 3;
        const char* rp = Ls + r * ROWB + HNOFF + q * 32;
        int4 h0 = *(const int4*)rp;
        int4 h1 = *(const int4*)(rp + 16);
        float* op = out + OUT_H + (size_t)(p0 + r) * 64 + q * 16;
        *(float4*)(op)      = float4{bf2f_lo(h0.x), bf2f_hi(h0.x), bf2f_lo(h0.y), bf2f_hi(h0.y)};
        *(float4*)(op + 4)  = float4{bf2f_lo(h0.z), bf2f_hi(h0.z), bf2f_lo(h0.w), bf2f_hi(h0.w)};
        *(float4*)(op + 8)  = float4{bf2f_lo(h1.x), bf2f_hi(h1.x), bf2f_lo(h1.y), bf2f_hi(h1.y)};
        *(float4*)(op + 12) = float4{bf2f_lo(h1.z), bf2f_hi(h1.z), bf2f_lo(h1.w), bf2f_hi(h1.w)};
    }

    // ---------------- GEMM3: hn[64x64] @ Wpost2'[64x160] -> lat (+dyn on w0) --------
    {
        // lat tiles {2w+2, 2w+3} = 32-col line w of every row (single-writer lines)
        f32x4 acc3[4][2];
#pragma unroll
        for (int m = 0; m < 4; ++m)
#pragma unroll
            for (int jj = 0; jj < 2; ++jj) acc3[m][jj] = (f32x4){0.f, 0.f, 0.f, 0.f};
#pragma unroll
        for (int s = 0; s < 2; ++s) {
            bf16x8 a[4];
#pragma unroll
            for (int m = 0; m < 4; ++m)
                a[m] = *(const bf16x8*)(Ls + (m * 16 + lr) * ROWB + HNOFF + s * 64 + lg * 16);
#pragma unroll
            for (int jj = 0; jj < 2; ++jj) {
                int n = 2 * w + 2 + jj;
                bf16x8 b =
                    *(const bf16x8*)(wpost_p + ((s * 160 + n * 16 + lr) * 32 + lg * 8));
#pragma unroll
                for (int m = 0; m < 4; ++m)
                    acc3[m][jj] = __builtin_amdgcn_mfma_f32_16x16x32_bf16(a[m], b,
                                                                          acc3[m][jj],
                                                                          0, 0, 0);
            }
        }
#pragma unroll
        for (int jj = 0; jj < 2; ++jj) {
            int L = 32 * w + 16 * jj + lr;            // lat col 0..127
            float bpv = b_post[L + 8];
#pragma unroll
            for (int m = 0; m < 4; ++m)
#pragma unroll
                for (int rr = 0; rr < 4; ++rr) {
                    int row = m * 16 + lg * 4 + rr;
                    out[OUT_LAT + (size_t)(p0 + row) * 128 + L] =
                        fast_tanh(acc3[m][jj][rr] + bpv);
                }
        }
        if (w == 0) {                                 // dyn tile (wave-uniform branch)
            f32x4 accD[4];
#pragma unroll
            for (int m = 0; m < 4; ++m) accD[m] = (f32x4){0.f, 0.f, 0.f, 0.f};
#pragma unroll
            for (int s = 0; s < 2; ++s) {
                bf16x8 b = *(const bf16x8*)(wpost_p + ((s * 160 + lr) * 32 + lg * 8));
#pragma unroll
                for (int m = 0; m < 4; ++m) {
                    bf16x8 a = *(const bf16x8*)(Ls + (m * 16 + lr) * ROWB + HNOFF +
                                                s * 64 + lg * 16);
                    accD[m] = __builtin_amdgcn_mfma_f32_16x16x32_bf16(a, b, accD[m], 0, 0, 0);
                }
            }
            if (lr < 8) {
                float bpv = b_post[lr];
#pragma unroll
                for (int m = 0; m < 4; ++m)
#pragma unroll
                    for (int rr = 0; rr < 4; ++rr) {
                        int row = m * 16 + lg * 4 + rr;
                        out[(size_t)(p0 + row) * 8 + lr] = fast_tanh(accD[m][rr] + bpv);
                    }
            }
        }
    }
}

extern "C" void kernel_launch(void* const* d_in, const int* in_sizes, int n_in,
                              void* d_out, int out_size, void* d_ws, size_t ws_size,
                              hipStream_t stream) {
    const float* dyn_in      = (const float*)d_in[0];
    const float* lat_prev    = (const float*)d_in[1];
    const float* lstm_c      = (const float*)d_in[2];
    const float* lstm_h      = (const float*)d_in[3];
    const int*   coming_from = (const int*)d_in[5];
    const float* W_pre  = (const float*)d_in[7];
    const float* b_pre  = (const float*)d_in[8];
    const float* W_ih   = (const float*)d_in[9];
    const float* W_hh   = (const float*)d_in[10];
    const float* b_lstm = (const float*)d_in[11];
    const float* W_post = (const float*)d_in[12];
    const float* b_post = (const float*)d_in[13];
    unsigned short* wsp = (unsigned short*)d_ws;

    prep_weights<<<(WTOTAL + 255) / 256, 256, 0, stream>>>(W_pre, W_ih, W_hh, W_post, wsp);
    knet_fused<<<NCELL / 64, 256, 0, stream>>>(dyn_in, lat_prev, lstm_c, lstm_h, coming_from,
                                               wsp, b_pre, b_lstm, b_post, (float*)d_out);
}